// Round 1
// baseline (50256.338 us; speedup 1.0000x reference)
//
#include <hip/hip_runtime.h>
#include <hip/hip_cooperative_groups.h>

namespace cg = cooperative_groups;

#define TT    512
#define BB    256
#define INDIM 8
#define HH    512
#define BH    (BB*HH)          // 131072 floats per hidden buffer

#define KC     32              // K-chunk staged in LDS
// tiles: BT=32 (batch), JT=16 (hidden cols) -> 8 x 32 = 256 tiles = grid

__global__ void __launch_bounds__(256, 1)
gru_persistent(const float* __restrict__ x,
               const float* __restrict__ Wih0, const float* __restrict__ Whh0,
               const float* __restrict__ bih0, const float* __restrict__ bhh0,
               const float* __restrict__ Wih1, const float* __restrict__ Whh1,
               const float* __restrict__ bih1, const float* __restrict__ bhh1,
               const float* __restrict__ Wout, const float* __restrict__ bout,
               float* __restrict__ out, float* __restrict__ ws)
{
    cg::grid_group grid = cg::this_grid();
    const int tid = threadIdx.x;
    const int blk = blockIdx.x;

    // XCD-aware tile mapping (blk%8 ~ XCD): all 8 b-tiles of a j-tile group on one XCD
    // so each XCD's weight working set (4/32 of 9MB ~ 1.1MB) stays L2-resident.
    const int xcd = blk & 7;
    const int r   = blk >> 3;          // 0..31
    const int jt  = xcd * 4 + (r & 3); // 0..31
    const int bt  = r >> 2;            // 0..7
    const int j0  = jt * 16;
    const int b0  = bt * 32;

    float* h0buf[2] = { ws,          ws +     BH };
    float* h1buf[2] = { ws + 2*BH,   ws + 3*BH   };

    // zero-init hidden state buffers (ws is poisoned 0xAA before every launch)
    for (int i = blk*256 + tid; i < 4*BH; i += 256*256) ws[i] = 0.0f;
    grid.sync();

    // LDS: ws9[k][j][g] with g in 0..8 padded to 12 (16B-aligned rows):
    //   g 0..2 = W_hh0 gates r,z,n ; g 3..5 = W_ih1 ; g 6..8 = W_hh1
    __shared__ float ws9 [KC*16*12];   // 24576 B
    __shared__ float hs01[KC*32*2];    // 8192 B  [k][b][{h0,h1}]

    const int tj = tid & 15;           // j within tile
    const int tb = tid >> 4;           // 0..15 -> b pair
    const int j  = j0 + tj;

    int cur = 0;
    for (int p = 0; p <= TT; ++p) {
        const float* h0_prev = h0buf[cur];      // h0[p-1]
        float*       h0_next = h0buf[cur^1];    // h0[p]
        const float* h1_prev = h1buf[cur];      // h1[p-2]
        float*       h1_next = h1buf[cur^1];    // h1[p-1]

        float accA[2][3] = {{0.f,0.f,0.f},{0.f,0.f,0.f}};  // h0 . W_hh0
        float accI[2][3] = {{0.f,0.f,0.f},{0.f,0.f,0.f}};  // h0 . W_ih1
        float accH[2][3] = {{0.f,0.f,0.f},{0.f,0.f,0.f}};  // h1 . W_hh1

        for (int kc = 0; kc < HH; kc += KC) {
            // ---- stage weights: 9 gate-rows x 16 j x KC k ----
            {
                const int lj  = tid & 15;
                const int lk2 = (tid >> 4) * 2;     // 0..30
                #pragma unroll
                for (int g = 0; g < 9; ++g) {
                    const float* M = (g < 3) ? Whh0 : ((g < 6) ? Wih1 : Whh1);
                    const int gg   = (g < 3) ? g    : ((g < 6) ? g - 3 : g - 6);
                    const float2 v = *(const float2*)(M + (size_t)(gg*HH + j0 + lj)*HH + kc + lk2);
                    ws9[((lk2+0)*16 + lj)*12 + g] = v.x;
                    ws9[((lk2+1)*16 + lj)*12 + g] = v.y;
                }
            }
            // ---- stage h0/h1 tiles, interleaved ----
            {
                const int lb  = tid & 31;
                const int lkk = (tid >> 5) * 4;     // 0..28
                const float4 a = *(const float4*)(h0_prev + (size_t)(b0+lb)*HH + kc + lkk);
                const float4 c = *(const float4*)(h1_prev + (size_t)(b0+lb)*HH + kc + lkk);
                hs01[((lkk+0)*32 + lb)*2 + 0] = a.x;  hs01[((lkk+0)*32 + lb)*2 + 1] = c.x;
                hs01[((lkk+1)*32 + lb)*2 + 0] = a.y;  hs01[((lkk+1)*32 + lb)*2 + 1] = c.y;
                hs01[((lkk+2)*32 + lb)*2 + 0] = a.z;  hs01[((lkk+2)*32 + lb)*2 + 1] = c.z;
                hs01[((lkk+3)*32 + lb)*2 + 0] = a.w;  hs01[((lkk+3)*32 + lb)*2 + 1] = c.w;
            }
            __syncthreads();
            #pragma unroll 8
            for (int k = 0; k < KC; ++k) {
                const float4 hv = *(const float4*)&hs01[(k*32 + tb*2)*2]; // h0[b],h1[b],h0[b+1],h1[b+1]
                const float* wrow = &ws9[(k*16 + tj)*12];
                const float4 w0 = *(const float4*)(wrow);      // A0 A1 A2 I0
                const float4 w1 = *(const float4*)(wrow + 4);  // I1 I2 H0 H1
                const float  w2 = wrow[8];                     // H2
                accA[0][0] += hv.x*w0.x; accA[0][1] += hv.x*w0.y; accA[0][2] += hv.x*w0.z;
                accI[0][0] += hv.x*w0.w; accI[0][1] += hv.x*w1.x; accI[0][2] += hv.x*w1.y;
                accH[0][0] += hv.y*w1.z; accH[0][1] += hv.y*w1.w; accH[0][2] += hv.y*w2;
                accA[1][0] += hv.z*w0.x; accA[1][1] += hv.z*w0.y; accA[1][2] += hv.z*w0.z;
                accI[1][0] += hv.z*w0.w; accI[1][1] += hv.z*w1.x; accI[1][2] += hv.z*w1.y;
                accH[1][0] += hv.w*w1.z; accH[1][1] += hv.w*w1.w; accH[1][2] += hv.w*w2;
            }
            __syncthreads();
        }

        // ---- layer 0 epilogue: h0[p] = GRU0(x[p], h0[p-1]) ----
        if (p < TT) {
            #pragma unroll
            for (int bi = 0; bi < 2; ++bi) {
                const int b = b0 + tb*2 + bi;
                const float* xr = x + ((size_t)p*BB + b)*INDIM;
                float ig[3];
                #pragma unroll
                for (int g = 0; g < 3; ++g) {
                    const float* wr = Wih0 + (size_t)(g*HH + j)*INDIM;
                    float s = bih0[g*HH + j];
                    #pragma unroll
                    for (int kk = 0; kk < INDIM; ++kk) s += xr[kk]*wr[kk];
                    ig[g] = s;
                }
                const float hr = accA[bi][0] + bhh0[j];
                const float hz = accA[bi][1] + bhh0[HH + j];
                const float hn = accA[bi][2] + bhh0[2*HH + j];
                const float rg = 1.0f/(1.0f + __expf(-(ig[0] + hr)));
                const float zg = 1.0f/(1.0f + __expf(-(ig[1] + hz)));
                const float ng = tanhf(ig[2] + rg*hn);
                const size_t idx = (size_t)b*HH + j;
                h0_next[idx] = (1.0f - zg)*ng + zg*h0_prev[idx];
            }
        }
        // ---- layer 1 epilogue: h1[p-1] = GRU1(h0[p-1], h1[p-2]) ----
        if (p >= 1) {
            #pragma unroll
            for (int bi = 0; bi < 2; ++bi) {
                const int b = b0 + tb*2 + bi;
                const float ir  = accI[bi][0] + bih1[j];
                const float iz  = accI[bi][1] + bih1[HH + j];
                const float in_ = accI[bi][2] + bih1[2*HH + j];
                const float hr  = accH[bi][0] + bhh1[j];
                const float hz  = accH[bi][1] + bhh1[HH + j];
                const float hn  = accH[bi][2] + bhh1[2*HH + j];
                const float rg = 1.0f/(1.0f + __expf(-(ir + hr)));
                const float zg = 1.0f/(1.0f + __expf(-(iz + hz)));
                const float ng = tanhf(in_ + rg*hn);
                const size_t idx = (size_t)b*HH + j;
                h1_next[idx] = (1.0f - zg)*ng + zg*h1_prev[idx];
            }
        }
        cur ^= 1;
        grid.sync();
    }

    // ---- linear head: out[b][o] = h1_final . Wout[o] + bout[o] ----
    const float* h1f = h1buf[cur];
    const int gidx = blk*256 + tid;
    if (gidx < BB*5) {
        const int b = gidx / 5;
        const int o = gidx - b*5;
        const float* hrow = h1f  + (size_t)b*HH;
        const float* wrow = Wout + (size_t)o*HH;
        float s = bout[o];
        for (int k2 = 0; k2 < HH; ++k2) s += hrow[k2]*wrow[k2];
        out[gidx] = s;
    }
}

extern "C" void kernel_launch(void* const* d_in, const int* in_sizes, int n_in,
                              void* d_out, int out_size, void* d_ws, size_t ws_size,
                              hipStream_t stream) {
    const float* x    = (const float*)d_in[0];
    const float* Wih0 = (const float*)d_in[1];
    const float* Whh0 = (const float*)d_in[2];
    const float* bih0 = (const float*)d_in[3];
    const float* bhh0 = (const float*)d_in[4];
    const float* Wih1 = (const float*)d_in[5];
    const float* Whh1 = (const float*)d_in[6];
    const float* bih1 = (const float*)d_in[7];
    const float* bhh1 = (const float*)d_in[8];
    const float* Wout = (const float*)d_in[9];
    const float* bout = (const float*)d_in[10];
    float* out = (float*)d_out;
    float* ws  = (float*)d_ws;   // needs 4*BH*4 = 2 MiB

    void* args[] = { (void*)&x, (void*)&Wih0, (void*)&Whh0, (void*)&bih0, (void*)&bhh0,
                     (void*)&Wih1, (void*)&Whh1, (void*)&bih1, (void*)&bhh1,
                     (void*)&Wout, (void*)&bout, (void*)&out, (void*)&ws };
    hipLaunchCooperativeKernel((const void*)gru_persistent,
                               dim3(256), dim3(256), args, 0, stream);
}

// Round 2
// 39819.986 us; speedup vs baseline: 1.2621x; 1.2621x over previous
//
#include <hip/hip_runtime.h>

typedef _Float16 half8 __attribute__((ext_vector_type(8)));
typedef float    f32x4 __attribute__((ext_vector_type(4)));

#define TT 512
#define BB 256
#define HH 512

// ---- workspace layout (bytes) ----
// [0      , 2MB )  h0f32[2], h1f32[2]      (4 x 512KB fp32 state)
// [2MB    , 3MB )  h0h[2], h1h[2]          (4 x 256KB f16 GEMM copies)
// [3MB    , 7.5MB) Wpk f16 [32 jg][144 nl][512 k]  (packed gate-major weights)
// [7.5MB  , ...)   flags: 8 ints (per-b-group barrier counters)
// total ~7.5MB + 32B

__global__ void prep_kernel(const float* __restrict__ Whh0,
                            const float* __restrict__ Wih1,
                            const float* __restrict__ Whh1,
                            float* __restrict__ ws)
{
    const int NW = 32*144*512;              // 2359296 packed weight elems
    _Float16* base16 = (_Float16*)(ws + 524288);
    _Float16* Wpk = base16 + 524288;
    int* flags = (int*)((char*)ws + 7864320);
    long long idx = (long long)blockIdx.x*256 + threadIdx.x;
    if (idx < NW) {
        int e = (int)idx;
        int jg  = e / (144*512);
        int rem = e % (144*512);
        int nl  = rem / 512;
        int k   = rem % 512;
        int jl  = (nl < 96) ? (nl & 15) : ((nl - 96) & 15);
        int j   = jg*16 + jl;
        float v;
        if (nl < 96) {
            int g6 = nl >> 4;                       // 0..5
            v = (g6 < 3) ? Whh0[(size_t)(g6*HH + j)*HH + k]
                         : Wih1[(size_t)((g6-3)*HH + j)*HH + k];
        } else {
            int g3 = (nl - 96) >> 4;                // 0..2
            v = Whh1[(size_t)(g3*HH + j)*HH + k];
        }
        Wpk[e] = (_Float16)v;
    } else if (idx < NW + 524288) {
        ws[idx - NW] = 0.0f;                        // zero fp32 h buffers
    } else if (idx < NW + 1048576) {
        base16[idx - NW - 524288] = (_Float16)0.0f; // zero f16 h buffers
    } else if (idx < NW + 1048576 + 8) {
        flags[idx - NW - 1048576] = 0;              // zero barrier counters
    }
}

// 256 blocks x 384 threads (6 waves). blk: jg = blk&31 (j-slice), bg = blk>>5 (b-group).
// 8 independent b-group recurrences; 32-block barrier per group per phase.
__global__ void __launch_bounds__(384, 1)
gru_main(const float* __restrict__ x,
         const float* __restrict__ Wih0, const float* __restrict__ bih0,
         const float* __restrict__ bhh0, const float* __restrict__ bih1,
         const float* __restrict__ bhh1, float* __restrict__ ws)
{
    const int tid = threadIdx.x;
    const int blk = blockIdx.x;
    const int jg  = blk & 31;
    const int bg  = blk >> 5;
    const int b0  = bg * 32;

    float* h0f[2] = { ws,          ws + 131072 };
    float* h1f[2] = { ws + 262144, ws + 393216 };
    _Float16* base16 = (_Float16*)(ws + 524288);
    _Float16* h0hb[2] = { base16,          base16 + 131072 };
    _Float16* h1hb[2] = { base16 + 262144, base16 + 393216 };
    const _Float16* Wpk = base16 + 524288;
    int* flags = (int*)((char*)ws + 7864320);

    // LDS: W chunk [144 n][64 k], A chunks [32 b][64 k] x2, C exchange [32][144]
    __shared__ __align__(16) _Float16 WbL[144*64];   // 18KB
    __shared__ __align__(16) _Float16 h0c[32*64];    // 4KB
    __shared__ __align__(16) _Float16 h1c[32*64];    // 4KB
    __shared__ __align__(16) float    Cx[32*144];    // 18KB

    const int lane = tid & 63;
    const int w    = tid >> 6;      // wave 0..5
    const int wb   = w & 1;         // b-tile 0..1
    const int wn   = w >> 1;        // n-group 0..2
    const int m    = lane & 15;
    const int q    = lane >> 4;
    const int xr   = m & 7;         // XOR swizzle key (row & 7)

    // precomputed LDS fragment element offsets (halves), s = kstep within 64-chunk
    int aoff[2], c0off[2], c1off[2], c2off[2];
    #pragma unroll
    for (int s = 0; s < 2; ++s) {
        int gg = (s*4 + q) ^ xr;    // swizzled 16B granule
        aoff[s]  = (wb*16 + m)*64 + gg*8;
        c0off[s] = (wn*16 + m)*64 + gg*8;
        c1off[s] = ((wn+3)*16 + m)*64 + gg*8;
        c2off[s] = (96 + wn*16 + m)*64 + gg*8;
    }

    const _Float16* WpkB = Wpk + (size_t)jg*144*512;

    for (int p = 0; p <= TT; ++p) {
        const _Float16* h0p = h0hb[(p+1)&1];   // h0[p-1] (A for gh0, gi1)
        const _Float16* h1p = h1hb[p&1];       // h1[p-2] (A for gh1)
        f32x4 acc0 = {0.f,0.f,0.f,0.f};
        f32x4 acc1 = {0.f,0.f,0.f,0.f};
        f32x4 acc2 = {0.f,0.f,0.f,0.f};

        for (int kc = 0; kc < HH; kc += 64) {
            // ---- stage W chunk (1152 granules) + h0/h1 chunks (256+256) ----
            for (int t = tid; t < 1664; t += 384) {
                const _Float16* gsrc;
                _Float16* ldst;
                if (t < 1152) {
                    int nl = t >> 3, g = t & 7;
                    gsrc = WpkB + (size_t)nl*512 + kc + g*8;
                    ldst = WbL + nl*64 + ((g ^ (nl & 7))*8);
                } else {
                    int t2 = t - 1152;
                    int mat = t2 >> 8, b = (t2 & 255) >> 3, g = t2 & 7;
                    const _Float16* src = mat ? h1p : h0p;
                    gsrc = src + (size_t)(b0 + b)*HH + kc + g*8;
                    ldst = (mat ? h1c : h0c) + b*64 + ((g ^ (b & 7))*8);
                }
                *(float4*)ldst = *(const float4*)gsrc;
            }
            __syncthreads();
            #pragma unroll
            for (int s = 0; s < 2; ++s) {
                half8 va0 = *(const half8*)&h0c[aoff[s]];
                half8 va1 = *(const half8*)&h1c[aoff[s]];
                half8 vb0 = *(const half8*)&WbL[c0off[s]];
                half8 vb1 = *(const half8*)&WbL[c1off[s]];
                half8 vb2 = *(const half8*)&WbL[c2off[s]];
                acc0 = __builtin_amdgcn_mfma_f32_16x16x32_f16(va0, vb0, acc0, 0, 0, 0);
                acc1 = __builtin_amdgcn_mfma_f32_16x16x32_f16(va0, vb1, acc1, 0, 0, 0);
                acc2 = __builtin_amdgcn_mfma_f32_16x16x32_f16(va1, vb2, acc2, 0, 0, 0);
            }
            __syncthreads();
        }

        // ---- C/D (col=lane&15, row=q*4+reg) -> LDS exchange ----
        #pragma unroll
        for (int r = 0; r < 4; ++r) {
            int brow = wb*16 + q*4 + r;
            Cx[brow*144 + wn*16 + m]      = acc0[r];
            Cx[brow*144 + (wn+3)*16 + m]  = acc1[r];
            Cx[brow*144 + 96 + wn*16 + m] = acc2[r];
        }
        __syncthreads();

        // ---- fused GRU epilogues ----
        const float* h0fp = h0f[(p+1)&1];
        float*       h0fn = h0f[p&1];
        const float* h1fp = h1f[p&1];
        float*       h1fn = h1f[(p+1)&1];
        _Float16*    h0hn = h0hb[p&1];
        _Float16*    h1hn = h1hb[(p+1)&1];

        for (int it = tid; it < 512; it += 384) {
            int bl = it & 31, jl = it >> 5;
            int b = b0 + bl, j = jg*16 + jl;
            const float* cr = &Cx[bl*144 + jl];
            if (p < TT) {   // layer 0: h0[p] = GRU0(x[p], h0[p-1])
                const float* xv = x + ((size_t)p*BB + b)*8;
                float s0 = bih0[j], s1 = bih0[HH + j], s2 = bih0[2*HH + j];
                const float* w0 = Wih0 + (size_t)j*8;
                const float* w1 = Wih0 + (size_t)(HH + j)*8;
                const float* w2 = Wih0 + (size_t)(2*HH + j)*8;
                #pragma unroll
                for (int kk = 0; kk < 8; ++kk) {
                    float xx = xv[kk];
                    s0 += xx*w0[kk]; s1 += xx*w1[kk]; s2 += xx*w2[kk];
                }
                float rg = 1.f/(1.f + __expf(-(s0 + cr[0]  + bhh0[j])));
                float zg = 1.f/(1.f + __expf(-(s1 + cr[16] + bhh0[HH + j])));
                float ng = tanhf(s2 + rg*(cr[32] + bhh0[2*HH + j]));
                float hp = h0fp[(size_t)b*HH + j];
                float hn = (1.f - zg)*ng + zg*hp;
                h0fn[(size_t)b*HH + j] = hn;
                h0hn[(size_t)b*HH + j] = (_Float16)hn;
            }
            if (p >= 1) {   // layer 1: h1[p-1] = GRU1(h0[p-1], h1[p-2])
                float rg = 1.f/(1.f + __expf(-(cr[48] + bih1[j]      + cr[96]  + bhh1[j])));
                float zg = 1.f/(1.f + __expf(-(cr[64] + bih1[HH+j]   + cr[112] + bhh1[HH+j])));
                float ng = tanhf(cr[80] + bih1[2*HH+j] + rg*(cr[128] + bhh1[2*HH+j]));
                float hp = h1fp[(size_t)b*HH + j];
                float hn = (1.f - zg)*ng + zg*hp;
                h1fn[(size_t)b*HH + j] = hn;
                h1hn[(size_t)b*HH + j] = (_Float16)hn;
            }
        }

        // ---- 32-block b-group barrier (monotonic counter, agent scope) ----
        __threadfence();
        __syncthreads();
        if (tid == 0) {
            __hip_atomic_fetch_add(&flags[bg], 1, __ATOMIC_ACQ_REL, __HIP_MEMORY_SCOPE_AGENT);
            const int target = 32*(p+1);
            while (__hip_atomic_load(&flags[bg], __ATOMIC_ACQUIRE, __HIP_MEMORY_SCOPE_AGENT) < target)
                __builtin_amdgcn_s_sleep(2);
        }
        __syncthreads();
    }
}

__global__ void head_kernel(const float* __restrict__ ws,
                            const float* __restrict__ Wout,
                            const float* __restrict__ bout,
                            float* __restrict__ out)
{
    const float* h1 = ws + 393216;   // h1f32 buf[1] = h1[511]
    int b = blockIdx.x;
    int lane = threadIdx.x;          // 64
    for (int o = 0; o < 5; ++o) {
        float s = 0.f;
        for (int k = lane; k < HH; k += 64)
            s += h1[(size_t)b*HH + k] * Wout[(size_t)o*HH + k];
        for (int off = 32; off > 0; off >>= 1)
            s += __shfl_xor(s, off, 64);
        if (lane == 0) out[b*5 + o] = s + bout[o];
    }
}

extern "C" void kernel_launch(void* const* d_in, const int* in_sizes, int n_in,
                              void* d_out, int out_size, void* d_ws, size_t ws_size,
                              hipStream_t stream) {
    const float* x    = (const float*)d_in[0];
    const float* Wih0 = (const float*)d_in[1];
    const float* Whh0 = (const float*)d_in[2];
    const float* bih0 = (const float*)d_in[3];
    const float* bhh0 = (const float*)d_in[4];
    const float* Wih1 = (const float*)d_in[5];
    const float* Whh1 = (const float*)d_in[6];
    const float* bih1 = (const float*)d_in[7];
    const float* bhh1 = (const float*)d_in[8];
    const float* Wout = (const float*)d_in[9];
    const float* bout = (const float*)d_in[10];
    float* out = (float*)d_out;
    float* ws  = (float*)d_ws;   // needs ~7.6 MB

    // 1) pack weights to f16 + zero state/flags
    const long long total = 32LL*144*512 + 524288 + 524288 + 8;
    int pblocks = (int)((total + 255) / 256);
    hipLaunchKernelGGL(prep_kernel, dim3(pblocks), dim3(256), 0, stream,
                       Whh0, Wih1, Whh1, ws);

    // 2) persistent recurrence (cooperative for co-residency; no grid.sync used)
    void* args[] = { (void*)&x, (void*)&Wih0, (void*)&bih0, (void*)&bhh0,
                     (void*)&bih1, (void*)&bhh1, (void*)&ws };
    hipLaunchCooperativeKernel((const void*)gru_main, dim3(256), dim3(384), args, 0, stream);

    // 3) linear head
    hipLaunchKernelGGL(head_kernel, dim3(256), dim3(64), 0, stream,
                       (const float*)ws, Wout, bout, out);
}

// Round 6
// 15624.649 us; speedup vs baseline: 3.2165x; 2.5485x over previous
//
#include <hip/hip_runtime.h>

typedef _Float16 half8 __attribute__((ext_vector_type(8)));
typedef float    f32x4 __attribute__((ext_vector_type(4)));

#define TT 512
#define BB 256
#define INDIM 8
#define HH 512

// ---- workspace layout ----
// floats [0, 131072)             : h1 final fp32 (head input; sentinel-filled by prep)
// halves b16 = ws+131072 floats  : h0h[2] (2x131072), h1h[2] (2x131072),
//                                  Wpk [32 jg][144 nl][512 k] (logical layout)
// bytes 6291456                  : flags, 8 groups x 32 ints (128B padded; 4 used)

__global__ void prep_kernel(const float* __restrict__ Whh0,
                            const float* __restrict__ Wih1,
                            const float* __restrict__ Whh1,
                            float* __restrict__ ws)
{
    const int NW = 32*144*512;                 // 2359296 packed weight halves
    _Float16* b16 = (_Float16*)(ws + 131072);
    _Float16* Wpk = b16 + 524288;
    int* flags = (int*)((char*)ws + 6291456);
    long long idx = (long long)blockIdx.x*256 + threadIdx.x;
    if (idx < NW) {
        int e   = (int)idx;
        int jg  = e / (144*512);
        int rem = e % (144*512);
        int nl  = rem >> 9;                    // 0..143 = g9*16 + m
        int k   = rem & 511;                   // logical k
        int g9  = nl >> 4;
        int m   = nl & 15;
        int j   = jg*16 + m;
        float v;
        if      (g9 < 3) v = Whh0[(size_t)(g9*HH + j)*HH + k];
        else if (g9 < 6) v = Wih1[(size_t)((g9-3)*HH + j)*HH + k];
        else             v = Whh1[(size_t)((g9-6)*HH + j)*HH + k];
        Wpk[e] = (_Float16)v;
    } else if (idx < NW + 524288) {
        b16[idx - NW] = (_Float16)0.0f;        // zero all 4 f16 h buffers
    } else if (idx < NW + 524288 + 256) {
        flags[idx - NW - 524288] = 0;          // zero padded barrier counters
    } else if (idx < NW + 524288 + 256 + 131072) {
        // sentinel: if gru_main silently fails to run, head output shifts
        // measurably off the bias-only value -> discriminates launch failure
        ws[idx - (NW + 524288 + 256)] = 1.0e-3f;
    }
}

// 128 blocks x 256 threads (4 waves), PLAIN launch (no cooperative API).
// bg = blk&3 (batch group of 64), jg = blk>>2 (j-slice of 16).
// Wave wv owns batch tile bg*64+wv*16 and ALL 9 gate-tiles of slice jg.
// k-steps (16 x K=32): 0..5 LDS, 6..9 VGPR cache, 10..15 streamed from L2.
__global__ void __launch_bounds__(256, 1)
gru_main(const float* __restrict__ x,
         const float* __restrict__ Wih0, const float* __restrict__ bih0,
         const float* __restrict__ bhh0, const float* __restrict__ bih1,
         const float* __restrict__ bhh1, float* __restrict__ ws)
{
    __shared__ __align__(16) _Float16 WlL[144*192];   // 55296 B

    const int tid = threadIdx.x;
    const int blk = blockIdx.x;        // 0..127
    const int bg  = blk & 3;
    const int jg  = blk >> 2;          // 0..31

    float* h1f = ws;
    _Float16* b16 = (_Float16*)(ws + 131072);
    _Float16* h0h[2] = { b16,          b16 + 131072 };
    _Float16* h1h[2] = { b16 + 262144, b16 + 393216 };
    const _Float16* Wpk = b16 + 524288;
    int* myflag = (int*)((char*)ws + 6291456) + bg*32;

    const _Float16* WpkB = Wpk + (size_t)jg*(144*512);

    // ---- one-time LDS fill: k-steps 0..5, XOR-swizzled granules ----
    // slot = gg ^ ((nl>>1)&7): XOR touches low 3 bits only, gg<24 -> slot<24.
    // Read pattern (stride 192 halves = 96 dwords ≡ 0 mod 32 banks) lands
    // uniform 8 lanes per 4-bank group = the wave64 b128 floor (no hotspot).
    for (int t = tid; t < 144*24; t += 256) {
        int nl = t / 24, gg = t % 24;
        int slot = gg ^ ((nl >> 1) & 7);
        *(float4*)&WlL[nl*192 + slot*8] = *(const float4*)&WpkB[(size_t)nl*512 + gg*8];
    }
    __syncthreads();

    const int lane = tid & 63;
    const int wv   = tid >> 6;          // wave 0..3 = batch tile
    const int m    = lane & 15;         // j-local / A,B frag row
    const int q    = lane >> 4;         // 0..3
    const int key  = (m >> 1) & 7;      // LDS swizzle key (matches fill)
    const int j    = jg*16 + m;
    const int bb   = bg*64 + wv*16;     // wave's batch base

    // ---- per-lane constants ----
    float w0[3][8];
    #pragma unroll
    for (int g = 0; g < 3; ++g)
        #pragma unroll
        for (int kk = 0; kk < 8; ++kk)
            w0[g][kk] = Wih0[(size_t)(g*HH + j)*INDIM + kk];
    const float br0  = bih0[j]      + bhh0[j];
    const float bz0  = bih0[HH+j]   + bhh0[HH+j];
    const float bni0 = bih0[2*HH+j];
    const float bnh0 = bhh0[2*HH+j];
    const float br1  = bih1[j]      + bhh1[j];
    const float bz1  = bih1[HH+j]   + bhh1[HH+j];
    const float bni1 = bih1[2*HH+j];
    const float bnh1 = bhh1[2*HH+j];

    // ---- VGPR B-cache: k-steps 6..9 (36 x half8 = 144 VGPRs) ----
    half8 Bc[4][9];
    #pragma unroll
    for (int s = 0; s < 4; ++s)
        #pragma unroll
        for (int g = 0; g < 9; ++g)
            Bc[s][g] = *(const half8*)&WpkB[(size_t)(g*16+m)*512 + (6+s)*32 + q*8];

    // fp32 hidden state carried in registers (lane owns rows q*4+r, col j)
    float h0pr[4] = {0.f,0.f,0.f,0.f};
    float h1pr[4] = {0.f,0.f,0.f,0.f};

    for (int p = 0; p <= TT; ++p) {
        const _Float16* h0p = h0h[(p+1)&1];   // h0[p-1]
        const _Float16* h1p = h1h[p&1];       // h1[p-2]
        const _Float16* a0base = h0p + (size_t)(bb + m)*HH + q*8;
        const _Float16* a1base = h1p + (size_t)(bb + m)*HH + q*8;

        half8 sA[2][9], sB[2][9], sC[2][9];
        // issue stream round 0 (steps 10,11) before compute
        #pragma unroll
        for (int t2 = 0; t2 < 2; ++t2)
            #pragma unroll
            for (int g = 0; g < 9; ++g)
                sA[t2][g] = *(const half8*)&WpkB[(size_t)(g*16+m)*512 + (10+t2)*32 + q*8];

        f32x4 acc[9];
        #pragma unroll
        for (int g = 0; g < 9; ++g) acc[g] = (f32x4){0.f,0.f,0.f,0.f};

        // ---- steps 0..5: B from LDS ----
        #pragma unroll
        for (int s = 0; s < 6; ++s) {
            half8 a0 = *(const half8*)(a0base + s*32);
            half8 a1 = *(const half8*)(a1base + s*32);
            #pragma unroll
            for (int g = 0; g < 9; ++g) {
                half8 bf = *(const half8*)&WlL[(g*16+m)*192 + (((s*4+q) ^ key))*8];
                acc[g] = __builtin_amdgcn_mfma_f32_16x16x32_f16((g < 6) ? a0 : a1, bf, acc[g], 0, 0, 0);
            }
        }
        // issue stream round 1 (steps 12,13)
        #pragma unroll
        for (int t2 = 0; t2 < 2; ++t2)
            #pragma unroll
            for (int g = 0; g < 9; ++g)
                sB[t2][g] = *(const half8*)&WpkB[(size_t)(g*16+m)*512 + (12+t2)*32 + q*8];
        // ---- steps 6..9: B from VGPR cache ----
        #pragma unroll
        for (int s = 0; s < 4; ++s) {
            half8 a0 = *(const half8*)(a0base + (6+s)*32);
            half8 a1 = *(const half8*)(a1base + (6+s)*32);
            #pragma unroll
            for (int g = 0; g < 9; ++g)
                acc[g] = __builtin_amdgcn_mfma_f32_16x16x32_f16((g < 6) ? a0 : a1, Bc[s][g], acc[g], 0, 0, 0);
        }
        // issue stream round 2 (steps 14,15)
        #pragma unroll
        for (int t2 = 0; t2 < 2; ++t2)
            #pragma unroll
            for (int g = 0; g < 9; ++g)
                sC[t2][g] = *(const half8*)&WpkB[(size_t)(g*16+m)*512 + (14+t2)*32 + q*8];
        // ---- steps 10..15: B from streamed registers ----
        #pragma unroll
        for (int s = 0; s < 6; ++s) {
            half8 a0 = *(const half8*)(a0base + (10+s)*32);
            half8 a1 = *(const half8*)(a1base + (10+s)*32);
            #pragma unroll
            for (int g = 0; g < 9; ++g) {
                half8 bf = (s < 2) ? sA[s][g] : (s < 4) ? sB[s-2][g] : sC[s-4][g];
                acc[g] = __builtin_amdgcn_mfma_f32_16x16x32_f16((g < 6) ? a0 : a1, bf, acc[g], 0, 0, 0);
            }
        }

        // ---- fused epilogues: lane owns (rows q*4+r, col j) ----
        _Float16* h0n = h0h[p&1];
        _Float16* h1n = h1h[(p+1)&1];
        if (p < TT) {
            #pragma unroll
            for (int r = 0; r < 4; ++r) {
                const int b = bb + q*4 + r;
                const float* xv = x + ((size_t)p*BB + b)*INDIM;
                float4 xa = *(const float4*)xv;
                float4 xb = *(const float4*)(xv + 4);
                float gr = xa.x*w0[0][0]+xa.y*w0[0][1]+xa.z*w0[0][2]+xa.w*w0[0][3]
                         + xb.x*w0[0][4]+xb.y*w0[0][5]+xb.z*w0[0][6]+xb.w*w0[0][7];
                float gz = xa.x*w0[1][0]+xa.y*w0[1][1]+xa.z*w0[1][2]+xa.w*w0[1][3]
                         + xb.x*w0[1][4]+xb.y*w0[1][5]+xb.z*w0[1][6]+xb.w*w0[1][7];
                float gn = xa.x*w0[2][0]+xa.y*w0[2][1]+xa.z*w0[2][2]+xa.w*w0[2][3]
                         + xb.x*w0[2][4]+xb.y*w0[2][5]+xb.z*w0[2][6]+xb.w*w0[2][7];
                float rg = 1.f/(1.f + __expf(-(gr + acc[0][r] + br0)));
                float zg = 1.f/(1.f + __expf(-(gz + acc[1][r] + bz0)));
                float ng = tanhf(gn + bni0 + rg*(acc[2][r] + bnh0));
                float hv = (1.f - zg)*ng + zg*h0pr[r];
                h0pr[r] = hv;
                h0n[(size_t)b*HH + j] = (_Float16)hv;
            }
        }
        if (p >= 1) {
            #pragma unroll
            for (int r = 0; r < 4; ++r) {
                const int b = bb + q*4 + r;
                float rg = 1.f/(1.f + __expf(-(acc[3][r] + acc[6][r] + br1)));
                float zg = 1.f/(1.f + __expf(-(acc[4][r] + acc[7][r] + bz1)));
                float ng = tanhf(acc[5][r] + bni1 + rg*(acc[8][r] + bnh1));
                float hv = (1.f - zg)*ng + zg*h1pr[r];
                h1pr[r] = hv;
                h1n[(size_t)b*HH + j] = (_Float16)hv;
                if (p == TT) h1f[(size_t)b*HH + j] = hv;
            }
        }

        // ---- rendezvous barrier (R2's proven sequence); skip after last phase:
        // the kernel boundary orders h1f before head_kernel.
        if (p < TT) {
            __threadfence();
            __syncthreads();
            if (tid == 0) {
                __hip_atomic_fetch_add(myflag, 1, __ATOMIC_ACQ_REL, __HIP_MEMORY_SCOPE_AGENT);
                const int target = 32*(p+1);
                while (__hip_atomic_load(myflag, __ATOMIC_ACQUIRE, __HIP_MEMORY_SCOPE_AGENT) < target)
                    __builtin_amdgcn_s_sleep(1);
            }
            __syncthreads();
        }
    }
}

__global__ void head_kernel(const float* __restrict__ ws,
                            const float* __restrict__ Wout,
                            const float* __restrict__ bout,
                            float* __restrict__ out)
{
    const float* h1 = ws;               // h1[511] fp32
    int b = blockIdx.x;
    int lane = threadIdx.x;             // 64
    for (int o = 0; o < 5; ++o) {
        float s = 0.f;
        for (int k = lane; k < HH; k += 64)
            s += h1[(size_t)b*HH + k] * Wout[(size_t)o*HH + k];
        for (int off = 32; off > 0; off >>= 1)
            s += __shfl_xor(s, off, 64);
        if (lane == 0) out[b*5 + o] = s + bout[o];
    }
}

extern "C" void kernel_launch(void* const* d_in, const int* in_sizes, int n_in,
                              void* d_out, int out_size, void* d_ws, size_t ws_size,
                              hipStream_t stream) {
    const float* x    = (const float*)d_in[0];
    const float* Wih0 = (const float*)d_in[1];
    const float* Whh0 = (const float*)d_in[2];
    const float* bih0 = (const float*)d_in[3];
    const float* bhh0 = (const float*)d_in[4];
    const float* Wih1 = (const float*)d_in[5];
    const float* Whh1 = (const float*)d_in[6];
    const float* bih1 = (const float*)d_in[7];
    const float* bhh1 = (const float*)d_in[8];
    const float* Wout = (const float*)d_in[9];
    const float* bout = (const float*)d_in[10];
    float* out = (float*)d_out;
    float* ws  = (float*)d_ws;   // needs ~6.3 MB

    // 1) pack weights to f16 + zero f16 state + zero flags + sentinel h1f
    const long long total = 32LL*144*512 + 524288 + 256 + 131072;
    int pblocks = (int)((total + 255) / 256);
    hipLaunchKernelGGL(prep_kernel, dim3(pblocks), dim3(256), 0, stream,
                       Whh0, Wih1, Whh1, ws);

    // 2) persistent recurrence — PLAIN launch (cooperative API under suspicion
    //    of silently rejecting R3/R4/R5). 128 blocks x 256 thr, 55.3KB LDS,
    //    ~350 VGPR -> >=1 block/CU on 256 CUs -> all blocks co-resident.
    hipLaunchKernelGGL(gru_main, dim3(128), dim3(256), 0, stream,
                       x, Wih0, bih0, bhh0, bih1, bhh1, ws);

    // 3) linear head
    hipLaunchKernelGGL(head_kernel, dim3(256), dim3(64), 0, stream,
                       (const float*)ws, Wout, bout, out);
}

// Round 7
// 10363.289 us; speedup vs baseline: 4.8495x; 1.5077x over previous
//
#include <hip/hip_runtime.h>

typedef _Float16 half8 __attribute__((ext_vector_type(8)));
typedef float    f32x4 __attribute__((ext_vector_type(4)));

#define TT 512
#define BB 256
#define INDIM 8
#define HH 512

// ---- workspace layout ----
// floats [0, 131072)             : h1 final fp32 (head input)
// halves b16 = ws+131072 floats  : h0h[2] (2x131072), h1h[2] (2x131072),
//                                  Wpk [32 jg][144 nl][512 k] (logical layout)
// bytes 6291456                  : flags, groups x 32 ints (128B padded)

__global__ void prep_kernel(const float* __restrict__ Whh0,
                            const float* __restrict__ Wih1,
                            const float* __restrict__ Whh1,
                            float* __restrict__ ws)
{
    const int NW = 32*144*512;                 // 2359296 packed weight halves
    _Float16* b16 = (_Float16*)(ws + 131072);
    _Float16* Wpk = b16 + 524288;
    int* flags = (int*)((char*)ws + 6291456);
    long long idx = (long long)blockIdx.x*256 + threadIdx.x;
    if (idx < NW) {
        int e   = (int)idx;
        int jg  = e / (144*512);
        int rem = e % (144*512);
        int nl  = rem >> 9;                    // 0..143 = g9*16 + m
        int k   = rem & 511;                   // logical k
        int g9  = nl >> 4;
        int m   = nl & 15;
        int j   = jg*16 + m;
        float v;
        if      (g9 < 3) v = Whh0[(size_t)(g9*HH + j)*HH + k];
        else if (g9 < 6) v = Wih1[(size_t)((g9-3)*HH + j)*HH + k];
        else             v = Whh1[(size_t)((g9-6)*HH + j)*HH + k];
        Wpk[e] = (_Float16)v;
    } else if (idx < NW + 524288) {
        b16[idx - NW] = (_Float16)0.0f;        // zero all 4 f16 h buffers
    } else if (idx < NW + 524288 + 256) {
        flags[idx - NW - 524288] = 0;          // zero padded barrier counters
    } else if (idx < NW + 524288 + 256 + 131072) {
        ws[idx - (NW + 524288 + 256)] = 1.0e-3f;  // sentinel (launch-failure canary)
    }
}

// 128 blocks x 256 threads (4 waves), PLAIN launch.
// bg = blk&3 (batch group of 64), jg = blk>>2 (j-slice of 16).
// Wave wv owns batch tile bg*64+wv*16 and ALL 9 gate-tiles of slice jg.
// k-steps (16 x K=32): 0..5 LDS, 6..7 VGPR cache, 8..15 pipelined from L2/LLC.
__global__ void __launch_bounds__(256, 1)
gru_main(const float* __restrict__ x,
         const float* __restrict__ Wih0, const float* __restrict__ bih0,
         const float* __restrict__ bhh0, const float* __restrict__ bih1,
         const float* __restrict__ bhh1, float* __restrict__ ws)
{
    __shared__ __align__(16) _Float16 WlL[144*192];   // 55296 B

    const int tid = threadIdx.x;
    const int blk = blockIdx.x;        // 0..127
    const int bg  = blk & 3;
    const int jg  = blk >> 2;          // 0..31

    float* h1f = ws;
    _Float16* b16 = (_Float16*)(ws + 131072);
    _Float16* h0h[2] = { b16,          b16 + 131072 };
    _Float16* h1h[2] = { b16 + 262144, b16 + 393216 };
    const _Float16* Wpk = b16 + 524288;
    int* myflag = (int*)((char*)ws + 6291456) + bg*32;

    const _Float16* WpkB = Wpk + (size_t)jg*(144*512);

    // ---- one-time LDS fill: k-steps 0..5, XOR-swizzled granules ----
    for (int t = tid; t < 144*24; t += 256) {
        int nl = t / 24, gg = t % 24;
        int slot = gg ^ ((nl >> 1) & 7);
        *(float4*)&WlL[nl*192 + slot*8] = *(const float4*)&WpkB[(size_t)nl*512 + gg*8];
    }
    __syncthreads();

    const int lane = tid & 63;
    const int wv   = tid >> 6;          // wave 0..3 = batch tile
    const int m    = lane & 15;         // j-local / A,B frag row
    const int q    = lane >> 4;         // 0..3
    const int key  = (m >> 1) & 7;      // LDS swizzle key (matches fill)
    const int j    = jg*16 + m;
    const int bb   = bg*64 + wv*16;     // wave's batch base

    // ---- per-lane constants ----
    float w0[3][8];
    #pragma unroll
    for (int g = 0; g < 3; ++g)
        #pragma unroll
        for (int kk = 0; kk < 8; ++kk)
            w0[g][kk] = Wih0[(size_t)(g*HH + j)*INDIM + kk];
    const float br0  = bih0[j]      + bhh0[j];
    const float bz0  = bih0[HH+j]   + bhh0[HH+j];
    const float bni0 = bih0[2*HH+j];
    const float bnh0 = bhh0[2*HH+j];
    const float br1  = bih1[j]      + bhh1[j];
    const float bz1  = bih1[HH+j]   + bhh1[HH+j];
    const float bni1 = bih1[2*HH+j];
    const float bnh1 = bhh1[2*HH+j];

    // ---- VGPR B-cache: k-steps 6..7 (18 x half8 = 72 VGPRs) ----
    half8 Bc[2][9];
    #pragma unroll
    for (int s = 0; s < 2; ++s)
        #pragma unroll
        for (int g = 0; g < 9; ++g)
            Bc[s][g] = *(const half8*)&WpkB[(size_t)(g*16+m)*512 + (6+s)*32 + q*8];

    // fp32 hidden state carried in registers (lane owns rows q*4+r, col j)
    float h0pr[4] = {0.f,0.f,0.f,0.f};
    float h1pr[4] = {0.f,0.f,0.f,0.f};

    for (int p = 0; p <= TT; ++p) {
        const _Float16* h0p = h0h[(p+1)&1];   // h0[p-1]
        const _Float16* h1p = h1h[p&1];       // h1[p-2]
        const _Float16* a0base = h0p + (size_t)(bb + m)*HH + q*8;
        const _Float16* a1base = h1p + (size_t)(bb + m)*HH + q*8;

        // ---- preload ALL A fragments (fresh h: the post-barrier critical
        // path). 32 b128 loads in flight at once -> one LLC latency, not 16.
        half8 a0s[16], a1s[16];
        #pragma unroll
        for (int s = 0; s < 16; ++s) {
            a0s[s] = *(const half8*)(a0base + s*32);
            a1s[s] = *(const half8*)(a1base + s*32);
        }

        f32x4 acc[9];
        #pragma unroll
        for (int g = 0; g < 9; ++g) acc[g] = (f32x4){0.f,0.f,0.f,0.f};

        // ---- steps 0..5: B from LDS ----
        #pragma unroll
        for (int s = 0; s < 6; ++s) {
            #pragma unroll
            for (int g = 0; g < 9; ++g) {
                half8 bf = *(const half8*)&WlL[(g*16+m)*192 + (((s*4+q) ^ key))*8];
                acc[g] = __builtin_amdgcn_mfma_f32_16x16x32_f16((g < 6) ? a0s[s] : a1s[s], bf, acc[g], 0, 0, 0);
            }
        }
        // ---- steps 6..7: B from VGPR cache ----
        #pragma unroll
        for (int s = 0; s < 2; ++s) {
            #pragma unroll
            for (int g = 0; g < 9; ++g)
                acc[g] = __builtin_amdgcn_mfma_f32_16x16x32_f16((g < 6) ? a0s[6+s] : a1s[6+s], Bc[s][g], acc[g], 0, 0, 0);
        }
        // ---- steps 8..15: B pipelined one step ahead from global ----
        half8 nb[9];
        #pragma unroll
        for (int g = 0; g < 9; ++g)
            nb[g] = *(const half8*)&WpkB[(size_t)(g*16+m)*512 + 8*32 + q*8];
        #pragma unroll
        for (int s = 8; s < 16; ++s) {
            half8 cb[9];
            #pragma unroll
            for (int g = 0; g < 9; ++g) cb[g] = nb[g];
            if (s < 15) {
                #pragma unroll
                for (int g = 0; g < 9; ++g)
                    nb[g] = *(const half8*)&WpkB[(size_t)(g*16+m)*512 + (s+1)*32 + q*8];
            }
            #pragma unroll
            for (int g = 0; g < 9; ++g)
                acc[g] = __builtin_amdgcn_mfma_f32_16x16x32_f16((g < 6) ? a0s[s] : a1s[s], cb[g], acc[g], 0, 0, 0);
        }

        // ---- fused epilogues: lane owns (rows q*4+r, col j) ----
        _Float16* h0n = h0h[p&1];
        _Float16* h1n = h1h[(p+1)&1];
        if (p < TT) {
            #pragma unroll
            for (int r = 0; r < 4; ++r) {
                const int b = bb + q*4 + r;
                const float* xv = x + ((size_t)p*BB + b)*INDIM;
                float4 xa = *(const float4*)xv;
                float4 xb = *(const float4*)(xv + 4);
                float gr = xa.x*w0[0][0]+xa.y*w0[0][1]+xa.z*w0[0][2]+xa.w*w0[0][3]
                         + xb.x*w0[0][4]+xb.y*w0[0][5]+xb.z*w0[0][6]+xb.w*w0[0][7];
                float gz = xa.x*w0[1][0]+xa.y*w0[1][1]+xa.z*w0[1][2]+xa.w*w0[1][3]
                         + xb.x*w0[1][4]+xb.y*w0[1][5]+xb.z*w0[1][6]+xb.w*w0[1][7];
                float gn = xa.x*w0[2][0]+xa.y*w0[2][1]+xa.z*w0[2][2]+xa.w*w0[2][3]
                         + xb.x*w0[2][4]+xb.y*w0[2][5]+xb.z*w0[2][6]+xb.w*w0[2][7];
                float rg = 1.f/(1.f + __expf(-(gr + acc[0][r] + br0)));
                float zg = 1.f/(1.f + __expf(-(gz + acc[1][r] + bz0)));
                float ng = tanhf(gn + bni0 + rg*(acc[2][r] + bnh0));
                float hv = (1.f - zg)*ng + zg*h0pr[r];
                h0pr[r] = hv;
                h0n[(size_t)b*HH + j] = (_Float16)hv;
            }
        }
        if (p >= 1) {
            #pragma unroll
            for (int r = 0; r < 4; ++r) {
                const int b = bb + q*4 + r;
                float rg = 1.f/(1.f + __expf(-(acc[3][r] + acc[6][r] + br1)));
                float zg = 1.f/(1.f + __expf(-(acc[4][r] + acc[7][r] + bz1)));
                float ng = tanhf(acc[5][r] + bni1 + rg*(acc[8][r] + bnh1));
                float hv = (1.f - zg)*ng + zg*h1pr[r];
                h1pr[r] = hv;
                h1n[(size_t)b*HH + j] = (_Float16)hv;
                if (p == TT) h1f[(size_t)b*HH + j] = hv;
            }
        }

        // ---- cheap rendezvous: ONE release fence + ONE acquire fence per
        // block per phase (tid0 only), relaxed coherent spin (no per-poll
        // buffer_inv). __syncthreads drains all waves' stores to L2 first
        // (m97: s_waitcnt vmcnt(0) before s_barrier); tid0's release fence
        // (buffer_wbl2) then publishes the whole block's stores to LLC.
        if (p < TT) {
            __syncthreads();
            if (tid == 0) {
                __builtin_amdgcn_fence(__ATOMIC_RELEASE, "agent");
                __hip_atomic_fetch_add(myflag, 1, __ATOMIC_RELAXED, __HIP_MEMORY_SCOPE_AGENT);
                const int target = 32*(p+1);
                while (__hip_atomic_load(myflag, __ATOMIC_RELAXED, __HIP_MEMORY_SCOPE_AGENT) < target)
                    __builtin_amdgcn_s_sleep(1);
                __builtin_amdgcn_fence(__ATOMIC_ACQUIRE, "agent");
            }
            __syncthreads();
        }
    }
}

__global__ void head_kernel(const float* __restrict__ ws,
                            const float* __restrict__ Wout,
                            const float* __restrict__ bout,
                            float* __restrict__ out)
{
    const float* h1 = ws;               // h1[511] fp32
    int b = blockIdx.x;
    int lane = threadIdx.x;             // 64
    for (int o = 0; o < 5; ++o) {
        float s = 0.f;
        for (int k = lane; k < HH; k += 64)
            s += h1[(size_t)b*HH + k] * Wout[(size_t)o*HH + k];
        for (int off = 32; off > 0; off >>= 1)
            s += __shfl_xor(s, off, 64);
        if (lane == 0) out[b*5 + o] = s + bout[o];
    }
}

extern "C" void kernel_launch(void* const* d_in, const int* in_sizes, int n_in,
                              void* d_out, int out_size, void* d_ws, size_t ws_size,
                              hipStream_t stream) {
    const float* x    = (const float*)d_in[0];
    const float* Wih0 = (const float*)d_in[1];
    const float* Whh0 = (const float*)d_in[2];
    const float* bih0 = (const float*)d_in[3];
    const float* bhh0 = (const float*)d_in[4];
    const float* Wih1 = (const float*)d_in[5];
    const float* Whh1 = (const float*)d_in[6];
    const float* bih1 = (const float*)d_in[7];
    const float* bhh1 = (const float*)d_in[8];
    const float* Wout = (const float*)d_in[9];
    const float* bout = (const float*)d_in[10];
    float* out = (float*)d_out;
    float* ws  = (float*)d_ws;   // needs ~6.3 MB

    // 1) pack weights to f16 + zero f16 state + zero flags + sentinel h1f
    const long long total = 32LL*144*512 + 524288 + 256 + 131072;
    int pblocks = (int)((total + 255) / 256);
    hipLaunchKernelGGL(prep_kernel, dim3(pblocks), dim3(256), 0, stream,
                       Whh0, Wih1, Whh1, ws);

    // 2) persistent recurrence — PLAIN launch (cooperative API silently
    //    rejected the R3-R5 configs). 128 blocks x 256 thr, 55.3KB LDS,
    //    1 block/CU -> all blocks co-resident on 256 CUs.
    hipLaunchKernelGGL(gru_main, dim3(128), dim3(256), 0, stream,
                       x, Wih0, bih0, bhh0, bih1, bhh1, ws);

    // 3) linear head
    hipLaunchKernelGGL(head_kernel, dim3(256), dim3(64), 0, stream,
                       (const float*)ws, Wout, bout, out);
}

// Round 8
// 9536.098 us; speedup vs baseline: 5.2701x; 1.0867x over previous
//
#include <hip/hip_runtime.h>

typedef _Float16 half8 __attribute__((ext_vector_type(8)));
typedef float    f32x4 __attribute__((ext_vector_type(4)));

#define TT 512
#define BB 256
#define INDIM 8
#define HH 512

// ---- workspace layout ----
// floats [0, 131072)             : h1 final fp32 (head input)
// halves b16 = ws+131072 floats  : h0h[2] (2x131072), h1h[2] (2x131072),
//                                  Wpk [32 jg][144 nl][512 k] (logical layout)
// bytes 6291456                  : flags, 4 groups x 32 ints (one 128B line each)

__global__ void prep_kernel(const float* __restrict__ Whh0,
                            const float* __restrict__ Wih1,
                            const float* __restrict__ Whh1,
                            float* __restrict__ ws)
{
    const int NW = 32*144*512;                 // 2359296 packed weight halves
    _Float16* b16 = (_Float16*)(ws + 131072);
    _Float16* Wpk = b16 + 524288;
    int* flags = (int*)((char*)ws + 6291456);
    long long idx = (long long)blockIdx.x*256 + threadIdx.x;
    if (idx < NW) {
        int e   = (int)idx;
        int jg  = e / (144*512);
        int rem = e % (144*512);
        int nl  = rem >> 9;                    // 0..143 = g9*16 + m
        int k   = rem & 511;                   // logical k
        int g9  = nl >> 4;
        int m   = nl & 15;
        int j   = jg*16 + m;
        float v;
        if      (g9 < 3) v = Whh0[(size_t)(g9*HH + j)*HH + k];
        else if (g9 < 6) v = Wih1[(size_t)((g9-3)*HH + j)*HH + k];
        else             v = Whh1[(size_t)((g9-6)*HH + j)*HH + k];
        Wpk[e] = (_Float16)v;
    } else if (idx < NW + 524288) {
        b16[idx - NW] = (_Float16)0.0f;        // zero all 4 f16 h buffers
    } else if (idx < NW + 524288 + 256) {
        flags[idx - NW - 524288] = 0;          // zero flag slots
    } else if (idx < NW + 524288 + 256 + 131072) {
        ws[idx - (NW + 524288 + 256)] = 1.0e-3f;  // sentinel canary
    }
}

// 128 blocks x 256 threads (4 waves), PLAIN launch.
// bg = blk&3 (batch group of 64), jg = blk>>2 (j-slice of 16).
// Cross-XCD h exchange via sc0+sc1 (LLC-coherent) loads/stores — NO fences,
// NO atomic RMW. Flag = per-block slot store; wave0 polls 32 slots in parallel.
__global__ void __launch_bounds__(256, 1)
gru_main(const float* __restrict__ x,
         const float* __restrict__ Wih0, const float* __restrict__ bih0,
         const float* __restrict__ bhh0, const float* __restrict__ bih1,
         const float* __restrict__ bhh1, float* __restrict__ ws)
{
    __shared__ __align__(16) _Float16 WlL[144*192];   // 55296 B

    const int tid = threadIdx.x;
    const int blk = blockIdx.x;        // 0..127
    const int bg  = blk & 3;
    const int jg  = blk >> 2;          // 0..31

    float* h1f = ws;
    _Float16* b16 = (_Float16*)(ws + 131072);
    _Float16* h0h[2] = { b16,          b16 + 131072 };
    _Float16* h1h[2] = { b16 + 262144, b16 + 393216 };
    const _Float16* Wpk = b16 + 524288;
    volatile int* grpflags = (int*)((char*)ws + 6291456) + bg*32;  // 128B line

    const _Float16* WpkB = Wpk + (size_t)jg*(144*512);

    // ---- one-time LDS fill: k-steps 0..5, XOR-swizzled granules ----
    for (int t = tid; t < 144*24; t += 256) {
        int nl = t / 24, gg = t % 24;
        int slot = gg ^ ((nl >> 1) & 7);
        *(float4*)&WlL[nl*192 + slot*8] = *(const float4*)&WpkB[(size_t)nl*512 + gg*8];
    }
    __syncthreads();

    const int lane = tid & 63;
    const int wv   = tid >> 6;          // wave 0..3 = batch tile
    const int m    = lane & 15;         // j-local / A,B frag row
    const int q    = lane >> 4;         // 0..3
    const int key  = (m >> 1) & 7;      // LDS swizzle key (matches fill)
    const int j    = jg*16 + m;
    const int bb   = bg*64 + wv*16;     // wave's batch base

    // ---- per-lane constants ----
    float w0[3][8];
    #pragma unroll
    for (int g = 0; g < 3; ++g)
        #pragma unroll
        for (int kk = 0; kk < 8; ++kk)
            w0[g][kk] = Wih0[(size_t)(g*HH + j)*INDIM + kk];
    const float br0  = bih0[j]      + bhh0[j];
    const float bz0  = bih0[HH+j]   + bhh0[HH+j];
    const float bni0 = bih0[2*HH+j];
    const float bnh0 = bhh0[2*HH+j];
    const float br1  = bih1[j]      + bhh1[j];
    const float bz1  = bih1[HH+j]   + bhh1[HH+j];
    const float bni1 = bih1[2*HH+j];
    const float bnh1 = bhh1[2*HH+j];

    // ---- VGPR B-cache: k-steps 6..7 ----
    half8 Bc[2][9];
    #pragma unroll
    for (int s = 0; s < 2; ++s)
        #pragma unroll
        for (int g = 0; g < 9; ++g)
            Bc[s][g] = *(const half8*)&WpkB[(size_t)(g*16+m)*512 + (6+s)*32 + q*8];

    // fp32 hidden state carried in registers (lane owns rows q*4+r, col j)
    float h0pr[4] = {0.f,0.f,0.f,0.f};
    float h1pr[4] = {0.f,0.f,0.f,0.f};

    for (int p = 0; p <= TT; ++p) {
        const _Float16* h0p = h0h[(p+1)&1];   // h0[p-1]
        const _Float16* h1p = h1h[p&1];       // h1[p-2]
        const _Float16* a0base = h0p + (size_t)(bb + m)*HH + q*8;
        const _Float16* a1base = h1p + (size_t)(bb + m)*HH + q*8;

        // ---- A fragments: 32 LLC-coherent loads in flight, one waitcnt ----
        half8 a0s[16], a1s[16];
        #pragma unroll
        for (int s = 0; s < 16; ++s) {
            asm volatile("global_load_dwordx4 %0, %1, off sc0 sc1"
                         : "=v"(a0s[s]) : "v"(a0base + s*32));
            asm volatile("global_load_dwordx4 %0, %1, off sc0 sc1"
                         : "=v"(a1s[s]) : "v"(a1base + s*32));
        }
        asm volatile("s_waitcnt vmcnt(0)"
            : "+v"(a0s[0]),"+v"(a0s[1]),"+v"(a0s[2]),"+v"(a0s[3]),
              "+v"(a0s[4]),"+v"(a0s[5]),"+v"(a0s[6]),"+v"(a0s[7]),
              "+v"(a0s[8]),"+v"(a0s[9]),"+v"(a0s[10]),"+v"(a0s[11]),
              "+v"(a0s[12]),"+v"(a0s[13]),"+v"(a0s[14]),"+v"(a0s[15]));
        asm volatile(""
            : "+v"(a1s[0]),"+v"(a1s[1]),"+v"(a1s[2]),"+v"(a1s[3]),
              "+v"(a1s[4]),"+v"(a1s[5]),"+v"(a1s[6]),"+v"(a1s[7]),
              "+v"(a1s[8]),"+v"(a1s[9]),"+v"(a1s[10]),"+v"(a1s[11]),
              "+v"(a1s[12]),"+v"(a1s[13]),"+v"(a1s[14]),"+v"(a1s[15]));

        f32x4 acc[9];
        #pragma unroll
        for (int g = 0; g < 9; ++g) acc[g] = (f32x4){0.f,0.f,0.f,0.f};

        // ---- steps 0..5: B from LDS ----
        #pragma unroll
        for (int s = 0; s < 6; ++s) {
            #pragma unroll
            for (int g = 0; g < 9; ++g) {
                half8 bf = *(const half8*)&WlL[(g*16+m)*192 + (((s*4+q) ^ key))*8];
                acc[g] = __builtin_amdgcn_mfma_f32_16x16x32_f16((g < 6) ? a0s[s] : a1s[s], bf, acc[g], 0, 0, 0);
            }
        }
        // ---- steps 6..7: B from VGPR cache ----
        #pragma unroll
        for (int s = 0; s < 2; ++s) {
            #pragma unroll
            for (int g = 0; g < 9; ++g)
                acc[g] = __builtin_amdgcn_mfma_f32_16x16x32_f16((g < 6) ? a0s[6+s] : a1s[6+s], Bc[s][g], acc[g], 0, 0, 0);
        }
        // ---- steps 8..15: B pipelined one step ahead from L2 (stays warm —
        // no more per-phase buffer_inv evicting it) ----
        half8 nb[9];
        #pragma unroll
        for (int g = 0; g < 9; ++g)
            nb[g] = *(const half8*)&WpkB[(size_t)(g*16+m)*512 + 8*32 + q*8];
        #pragma unroll
        for (int s = 8; s < 16; ++s) {
            half8 cb[9];
            #pragma unroll
            for (int g = 0; g < 9; ++g) cb[g] = nb[g];
            if (s < 15) {
                #pragma unroll
                for (int g = 0; g < 9; ++g)
                    nb[g] = *(const half8*)&WpkB[(size_t)(g*16+m)*512 + (s+1)*32 + q*8];
            }
            #pragma unroll
            for (int g = 0; g < 9; ++g)
                acc[g] = __builtin_amdgcn_mfma_f32_16x16x32_f16((g < 6) ? a0s[s] : a1s[s], cb[g], acc[g], 0, 0, 0);
        }

        // ---- fused epilogues: h stores are sc0+sc1 write-through to LLC ----
        _Float16* h0n = h0h[p&1];
        _Float16* h1n = h1h[(p+1)&1];
        if (p < TT) {
            #pragma unroll
            for (int r = 0; r < 4; ++r) {
                const int b = bb + q*4 + r;
                const float* xv = x + ((size_t)p*BB + b)*INDIM;
                float4 xa = *(const float4*)xv;
                float4 xb = *(const float4*)(xv + 4);
                float gr = xa.x*w0[0][0]+xa.y*w0[0][1]+xa.z*w0[0][2]+xa.w*w0[0][3]
                         + xb.x*w0[0][4]+xb.y*w0[0][5]+xb.z*w0[0][6]+xb.w*w0[0][7];
                float gz = xa.x*w0[1][0]+xa.y*w0[1][1]+xa.z*w0[1][2]+xa.w*w0[1][3]
                         + xb.x*w0[1][4]+xb.y*w0[1][5]+xb.z*w0[1][6]+xb.w*w0[1][7];
                float gn = xa.x*w0[2][0]+xa.y*w0[2][1]+xa.z*w0[2][2]+xa.w*w0[2][3]
                         + xb.x*w0[2][4]+xb.y*w0[2][5]+xb.z*w0[2][6]+xb.w*w0[2][7];
                float rg = 1.f/(1.f + __expf(-(gr + acc[0][r] + br0)));
                float zg = 1.f/(1.f + __expf(-(gz + acc[1][r] + bz0)));
                float ng = tanhf(gn + bni0 + rg*(acc[2][r] + bnh0));
                float hv = (1.f - zg)*ng + zg*h0pr[r];
                h0pr[r] = hv;
                _Float16 hv16 = (_Float16)hv;
                asm volatile("global_store_short %0, %1, off sc0 sc1"
                             :: "v"(h0n + (size_t)b*HH + j), "v"(hv16) : "memory");
            }
        }
        if (p >= 1) {
            #pragma unroll
            for (int r = 0; r < 4; ++r) {
                const int b = bb + q*4 + r;
                float rg = 1.f/(1.f + __expf(-(acc[3][r] + acc[6][r] + br1)));
                float zg = 1.f/(1.f + __expf(-(acc[4][r] + acc[7][r] + bz1)));
                float ng = tanhf(acc[5][r] + bni1 + rg*(acc[8][r] + bnh1));
                float hv = (1.f - zg)*ng + zg*h1pr[r];
                h1pr[r] = hv;
                _Float16 hv16 = (_Float16)hv;
                asm volatile("global_store_short %0, %1, off sc0 sc1"
                             :: "v"(h1n + (size_t)b*HH + j), "v"(hv16) : "memory");
                if (p == TT) h1f[(size_t)b*HH + j] = hv;   // kernel-boundary flush
            }
        }

        // ---- fence-free rendezvous ----
        // per-wave vmcnt(0): this wave's sc1 stores are at the LLC; syncthreads
        // collects all 4 waves; tid0 then publishes the block's slot (plain
        // sc1 store, no RMW); wave0 polls all 32 slots lane-parallel.
        if (p < TT) {
            asm volatile("s_waitcnt vmcnt(0)" ::: "memory");
            __syncthreads();
            if (tid == 0) grpflags[jg] = p + 1;
            if (tid < 64) {
                while (true) {
                    int v = grpflags[lane & 31];
                    if (__all(v > p)) break;
                    __builtin_amdgcn_s_sleep(1);
                }
            }
            __syncthreads();
        }
    }
}

__global__ void head_kernel(const float* __restrict__ ws,
                            const float* __restrict__ Wout,
                            const float* __restrict__ bout,
                            float* __restrict__ out)
{
    const float* h1 = ws;               // h1[511] fp32
    int b = blockIdx.x;
    int lane = threadIdx.x;             // 64
    for (int o = 0; o < 5; ++o) {
        float s = 0.f;
        for (int k = lane; k < HH; k += 64)
            s += h1[(size_t)b*HH + k] * Wout[(size_t)o*HH + k];
        for (int off = 32; off > 0; off >>= 1)
            s += __shfl_xor(s, off, 64);
        if (lane == 0) out[b*5 + o] = s + bout[o];
    }
}

extern "C" void kernel_launch(void* const* d_in, const int* in_sizes, int n_in,
                              void* d_out, int out_size, void* d_ws, size_t ws_size,
                              hipStream_t stream) {
    const float* x    = (const float*)d_in[0];
    const float* Wih0 = (const float*)d_in[1];
    const float* Whh0 = (const float*)d_in[2];
    const float* bih0 = (const float*)d_in[3];
    const float* bhh0 = (const float*)d_in[4];
    const float* Wih1 = (const float*)d_in[5];
    const float* Whh1 = (const float*)d_in[6];
    const float* bih1 = (const float*)d_in[7];
    const float* bhh1 = (const float*)d_in[8];
    const float* Wout = (const float*)d_in[9];
    const float* bout = (const float*)d_in[10];
    float* out = (float*)d_out;
    float* ws  = (float*)d_ws;   // needs ~6.3 MB

    // 1) pack weights to f16 + zero f16 state + zero flags + sentinel h1f
    const long long total = 32LL*144*512 + 524288 + 256 + 131072;
    int pblocks = (int)((total + 255) / 256);
    hipLaunchKernelGGL(prep_kernel, dim3(pblocks), dim3(256), 0, stream,
                       Whh0, Wih1, Whh1, ws);

    // 2) persistent recurrence — plain launch, 128 blocks x 256 thr,
    //    1 block/CU, all co-resident.
    hipLaunchKernelGGL(gru_main, dim3(128), dim3(256), 0, stream,
                       x, Wih0, bih0, bhh0, bih1, bhh1, ws);

    // 3) linear head
    hipLaunchKernelGGL(head_kernel, dim3(256), dim3(64), 0, stream,
                       (const float*)ws, Wout, bout, out);
}